// Round 1
// baseline (536.527 us; speedup 1.0000x reference)
//
#include <hip/hip_runtime.h>

// Quantize (VQ-VAE): BatchNorm1d(batch stats) -> nearest codebook (argmin L2) -> gather + diff
// Shapes: x [32,2048,256] f32 -> N=65536 rows, D=256; embed [256,1024] f32 (K=1024)
// Outputs: quantize [N*D] f32, then diff scalar (out_size = N*D + 1)

#define N_ROWS 65536
#define DIM 256
#define KCODES 1024
#define BN_EPS_F 1e-5f

#define STAT_BLOCKS 512      // 128 rows each
#define BM 128               // row tile
#define BNT 128              // code tile (8 tiles cover K=1024)
#define BK 32                // d-chunk
#define AS_STRIDE 132        // 128 + 4 pad (keeps 16B alignment, cuts bank conflicts)
#define E_BLOCKS 16384       // gather blocks: 4 rows each

// ---------------- BN statistics: stage 1 (per-block column partials) ----------------
__global__ void bn_partial(const float* __restrict__ x, float* __restrict__ pSum,
                           float* __restrict__ pSq) {
    int t = threadIdx.x;                 // column 0..255
    int b = blockIdx.x;                  // 0..511
    long base = (long)b * 128 * DIM;
    float s = 0.f, q = 0.f;
    for (int r = 0; r < 128; ++r) {
        float v = x[base + (long)r * DIM + t];
        s += v; q += v * v;
    }
    pSum[b * DIM + t] = s;
    pSq[b * DIM + t] = q;
}

// ---------------- BN statistics: stage 2 (finalize scale/shift) ----------------
__global__ void bn_finalize(const float* __restrict__ pSum, const float* __restrict__ pSq,
                            const float* __restrict__ gamma, const float* __restrict__ beta,
                            float* __restrict__ scale, float* __restrict__ shift) {
    int t = threadIdx.x;                 // column
    float s = 0.f, q = 0.f;
    for (int b = 0; b < STAT_BLOCKS; ++b) {
        s += pSum[b * DIM + t];
        q += pSq[b * DIM + t];
    }
    float mean = s * (1.0f / (float)N_ROWS);
    float var  = q * (1.0f / (float)N_ROWS) - mean * mean;  // biased var (ddof=0)
    var = fmaxf(var, 0.f);
    float sc = gamma[t] * rsqrtf(var + BN_EPS_F);
    scale[t] = sc;
    shift[t] = beta[t] - mean * sc;
}

// ---------------- embed prep: transpose to [K][D] + squared norms ----------------
__global__ void embed_prep(const float* __restrict__ embed, float* __restrict__ embedT,
                           float* __restrict__ enorm) {
    __shared__ float T[32][33];
    __shared__ float ps[8][32];
    int tid = threadIdx.x;
    int tx = tid & 31;       // k offset within tile
    int ty = tid >> 5;       // 0..7 d sub-row
    int k0 = blockIdx.x * 32;
    float sq = 0.f;
    for (int d0 = 0; d0 < DIM; d0 += 32) {
        __syncthreads();
        #pragma unroll
        for (int p = 0; p < 4; ++p) {
            int dl = ty + p * 8;
            float v = embed[(long)(d0 + dl) * KCODES + k0 + tx];
            T[tx][dl] = v;
            sq += v * v;
        }
        __syncthreads();
        int kr = tid >> 3;            // 0..31
        int dc = (tid & 7) * 4;       // 0..28
        float4 w = make_float4(T[kr][dc], T[kr][dc + 1], T[kr][dc + 2], T[kr][dc + 3]);
        *(float4*)&embedT[(long)(k0 + kr) * DIM + d0 + dc] = w;
    }
    ps[ty][tx] = sq;
    __syncthreads();
    if (ty == 0) {
        float s = 0.f;
        #pragma unroll
        for (int i = 0; i < 8; ++i) s += ps[i][tx];
        enorm[k0 + tx] = s;
    }
}

// ---------------- fused distance GEMM + argmin ----------------
// score(n,k) = ||e_k||^2 - 2 * dot(xn_n, e_k)   (||xn||^2 dropped: argmin-invariant)
__global__ __launch_bounds__(256, 2) void dist_argmin(
    const float* __restrict__ x, const float* __restrict__ embed,
    const float* __restrict__ scale, const float* __restrict__ shift,
    const float* __restrict__ enorm, int* __restrict__ bestIdx) {
    __shared__ __attribute__((aligned(16))) float As[BK][AS_STRIDE];  // [d'][row]
    __shared__ __attribute__((aligned(16))) float Bs[BK][AS_STRIDE];  // [d'][code]
    __shared__ __attribute__((aligned(16))) float sc_s[DIM];
    __shared__ __attribute__((aligned(16))) float sh_s[DIM];

    int tid = threadIdx.x;
    int tx = tid & 15;       // code group 0..15
    int ty = tid >> 4;       // row group 0..15
    long row0 = (long)blockIdx.x * BM;

    sc_s[tid] = scale[tid];
    sh_s[tid] = shift[tid];

    float runV[8];
    int   runI[8];
    #pragma unroll
    for (int i = 0; i < 8; ++i) { runV[i] = 3.4e38f; runI[i] = 0; }

    for (int ct = 0; ct < KCODES / BNT; ++ct) {
        float acc[8][8];
        #pragma unroll
        for (int i = 0; i < 8; ++i)
            #pragma unroll
            for (int j = 0; j < 8; ++j) acc[i][j] = 0.f;

        for (int dk = 0; dk < DIM; dk += BK) {
            __syncthreads();  // previous compute done before restaging
            // ---- stage A (normalize on the fly): As[d'][r]
            {
                int dq = tid & 7;            // d' = dq*4 .. dq*4+3
                int rb = tid >> 3;           // 0..31
                float4 scv = *(const float4*)&sc_s[dk + dq * 4];
                float4 shv = *(const float4*)&sh_s[dk + dq * 4];
                #pragma unroll
                for (int p = 0; p < 4; ++p) {
                    int r = rb + p * 32;
                    float4 v = *(const float4*)&x[(row0 + r) * DIM + dk + dq * 4];
                    As[dq * 4 + 0][r] = v.x * scv.x + shv.x;
                    As[dq * 4 + 1][r] = v.y * scv.y + shv.y;
                    As[dq * 4 + 2][r] = v.z * scv.z + shv.z;
                    As[dq * 4 + 3][r] = v.w * scv.w + shv.w;
                }
            }
            // ---- stage B: Bs[d'][c]
            {
                int c4 = tid & 31;           // code 4-group
                int dr = tid >> 5;           // 0..7
                #pragma unroll
                for (int p = 0; p < 4; ++p) {
                    int dl = dr + p * 8;
                    float4 v = *(const float4*)&embed[(long)(dk + dl) * KCODES + ct * BNT + c4 * 4];
                    *(float4*)&Bs[dl][c4 * 4] = v;
                }
            }
            __syncthreads();
            // ---- compute: 8x8 micro-tile, cols split {tx*4..+3} U {64+tx*4..+3} (bank-friendly)
            #pragma unroll 8
            for (int kk = 0; kk < BK; ++kk) {
                float4 a0 = *(const float4*)&As[kk][ty * 8];
                float4 a1 = *(const float4*)&As[kk][ty * 8 + 4];
                float4 b0 = *(const float4*)&Bs[kk][tx * 4];
                float4 b1 = *(const float4*)&Bs[kk][64 + tx * 4];
                float a[8] = {a0.x, a0.y, a0.z, a0.w, a1.x, a1.y, a1.z, a1.w};
                float b[8] = {b0.x, b0.y, b0.z, b0.w, b1.x, b1.y, b1.z, b1.w};
                #pragma unroll
                for (int i = 0; i < 8; ++i)
                    #pragma unroll
                    for (int j = 0; j < 8; ++j) acc[i][j] += a[i] * b[j];
            }
        }
        // ---- epilogue: scores + running argmin
        float4 en0 = *(const float4*)&enorm[ct * BNT + tx * 4];
        float4 en1 = *(const float4*)&enorm[ct * BNT + 64 + tx * 4];
        float en[8] = {en0.x, en0.y, en0.z, en0.w, en1.x, en1.y, en1.z, en1.w};
        int col0 = ct * BNT + tx * 4;
        int col1 = ct * BNT + 64 + tx * 4;
        #pragma unroll
        for (int i = 0; i < 8; ++i) {
            float bv = 3.4e38f;
            int bi = 0;
            #pragma unroll
            for (int j = 0; j < 8; ++j) {
                float s = en[j] - 2.0f * acc[i][j];
                int col = (j < 4) ? (col0 + j) : (col1 + (j - 4));
                if (s < bv) { bv = s; bi = col; }       // ascending cols: first-min kept
            }
            // butterfly min across the 16 lanes sharing these rows (tie -> smaller idx)
            #pragma unroll
            for (int m = 1; m < 16; m <<= 1) {
                float ov = __shfl_xor(bv, m);
                int   oi = __shfl_xor(bi, m);
                if (ov < bv || (ov == bv && oi < bi)) { bv = ov; bi = oi; }
            }
            if (bv < runV[i] || (bv == runV[i] && bi < runI[i])) { runV[i] = bv; runI[i] = bi; }
        }
    }
    if (tx == 0) {
        #pragma unroll
        for (int i = 0; i < 8; ++i) bestIdx[row0 + ty * 8 + i] = runI[i];
    }
}

// ---------------- gather codebook rows + diff partials ----------------
__global__ void gather_out(const float* __restrict__ x, const float* __restrict__ embedT,
                           const float* __restrict__ scale, const float* __restrict__ shift,
                           const int* __restrict__ bestIdx, float* __restrict__ out,
                           float* __restrict__ diffPart) {
    __shared__ float wsum[4];
    int tid = threadIdx.x;
    int wave = tid >> 6, lane = tid & 63;
    long row = (long)blockIdx.x * 4 + wave;
    int k = bestIdx[row];
    int d0 = lane * 4;
    float4 q  = *(const float4*)&embedT[(long)k * DIM + d0];
    float4 xv = *(const float4*)&x[row * DIM + d0];
    float4 sc = *(const float4*)&scale[d0];
    float4 sh = *(const float4*)&shift[d0];
    float xn0 = xv.x * sc.x + sh.x;
    float xn1 = xv.y * sc.y + sh.y;
    float xn2 = xv.z * sc.z + sh.z;
    float xn3 = xv.w * sc.w + sh.w;
    *(float4*)&out[row * DIM + d0] = q;
    float d0f = q.x - xn0, d1f = q.y - xn1, d2f = q.z - xn2, d3f = q.w - xn3;
    float dsq = d0f * d0f + d1f * d1f + d2f * d2f + d3f * d3f;
    #pragma unroll
    for (int m = 32; m; m >>= 1) dsq += __shfl_xor(dsq, m);
    if (lane == 0) wsum[wave] = dsq;
    __syncthreads();
    if (tid == 0) diffPart[blockIdx.x] = wsum[0] + wsum[1] + wsum[2] + wsum[3];
}

// ---------------- final diff reduce ----------------
__global__ void diff_final(const float* __restrict__ diffPart, float* __restrict__ outDiff) {
    __shared__ float s[256];
    int tid = threadIdx.x;
    float a = 0.f;
    for (int i = tid; i < E_BLOCKS; i += 256) a += diffPart[i];
    s[tid] = a;
    __syncthreads();
    for (int st = 128; st; st >>= 1) {
        if (tid < st) s[tid] += s[tid + st];
        __syncthreads();
    }
    if (tid == 0) outDiff[0] = s[0] * (1.0f / (float)(N_ROWS * DIM));
}

extern "C" void kernel_launch(void* const* d_in, const int* in_sizes, int n_in,
                              void* d_out, int out_size, void* d_ws, size_t ws_size,
                              hipStream_t stream) {
    const float* x     = (const float*)d_in[0];
    const float* embed = (const float*)d_in[1];
    const float* gamma = (const float*)d_in[2];
    const float* beta  = (const float*)d_in[3];
    float* out = (float*)d_out;

    // ws layout (floats)
    float* w = (float*)d_ws;
    float* pSum    = w;                          // 512*256
    float* pSq     = w + 131072;                 // 512*256
    float* scale   = w + 262144;                 // 256
    float* shift   = w + 262400;                 // 256
    float* embedT  = w + 262656;                 // 1024*256
    float* enorm   = w + 524800;                 // 1024
    int*   bestIdx = (int*)(w + 525824);         // 65536
    float* diffPart= w + 591360;                 // 16384
    // total ~2.43 MB

    bn_partial<<<STAT_BLOCKS, 256, 0, stream>>>(x, pSum, pSq);
    bn_finalize<<<1, 256, 0, stream>>>(pSum, pSq, gamma, beta, scale, shift);
    embed_prep<<<KCODES / 32, 256, 0, stream>>>(embed, embedT, enorm);
    dist_argmin<<<N_ROWS / BM, 256, 0, stream>>>(x, embed, scale, shift, enorm, bestIdx);
    gather_out<<<E_BLOCKS, 256, 0, stream>>>(x, embedT, scale, shift, bestIdx, out, diffPart);
    diff_final<<<1, 256, 0, stream>>>(diffPart, out + (long)N_ROWS * DIM);
}

// Round 7
// 505.971 us; speedup vs baseline: 1.0604x; 1.0604x over previous
//
#include <hip/hip_runtime.h>

// VQ-VAE Quantize: BN1d(batch stats) -> argmin L2 vs codebook -> gather + diff
// R7: R1's exact fp32 pipeline (the only score arithmetic proven to match the
// np reference's fp32-level argmin on these deterministic inputs), restructured
// bit-safely: code-range split (2 blocks per row-tile -> 1024 blocks, occupancy
// 2->4 blocks/CU) + deterministic half-merge. All score expressions, summation
// orders, and ws byte offsets are R1-verbatim.

#define N_ROWS 65536
#define DIM 256
#define KCODES 1024
#define BN_EPS_F 1e-5f

#define STAT_BLOCKS 512      // 128 rows each
#define BM 128               // row tile
#define BNT 128              // code tile (4 tiles per half)
#define BK 32                // d-chunk
#define AS_STRIDE 132        // 128 + 4 pad
#define E_BLOCKS 16384       // gather blocks: 4 rows each

// ---------------- BN statistics: stage 1 (per-block column partials) ----------------
__global__ void bn_partial(const float* __restrict__ x, float* __restrict__ pSum,
                           float* __restrict__ pSq) {
    int t = threadIdx.x;                 // column 0..255
    int b = blockIdx.x;                  // 0..511
    long base = (long)b * 128 * DIM;
    float s = 0.f, q = 0.f;
    for (int r = 0; r < 128; ++r) {
        float v = x[base + (long)r * DIM + t];
        s += v; q += v * v;
    }
    pSum[b * DIM + t] = s;
    pSq[b * DIM + t] = q;
}

// ---------------- BN statistics: stage 2 (finalize scale/shift) ----------------
__global__ void bn_finalize(const float* __restrict__ pSum, const float* __restrict__ pSq,
                            const float* __restrict__ gamma, const float* __restrict__ beta,
                            float* __restrict__ scale, float* __restrict__ shift) {
    int t = threadIdx.x;                 // column
    float s = 0.f, q = 0.f;
    for (int b = 0; b < STAT_BLOCKS; ++b) {
        s += pSum[b * DIM + t];
        q += pSq[b * DIM + t];
    }
    float mean = s * (1.0f / (float)N_ROWS);
    float var  = q * (1.0f / (float)N_ROWS) - mean * mean;  // biased var (ddof=0)
    var = fmaxf(var, 0.f);
    float sc = gamma[t] * rsqrtf(var + BN_EPS_F);
    scale[t] = sc;
    shift[t] = beta[t] - mean * sc;
}

// ---------------- embed prep: transpose to [K][D] + squared norms ----------------
__global__ void embed_prep(const float* __restrict__ embed, float* __restrict__ embedT,
                           float* __restrict__ enorm) {
    __shared__ float T[32][33];
    __shared__ float ps[8][32];
    int tid = threadIdx.x;
    int tx = tid & 31;       // k offset within tile
    int ty = tid >> 5;       // 0..7 d sub-row
    int k0 = blockIdx.x * 32;
    float sq = 0.f;
    for (int d0 = 0; d0 < DIM; d0 += 32) {
        __syncthreads();
        #pragma unroll
        for (int p = 0; p < 4; ++p) {
            int dl = ty + p * 8;
            float v = embed[(long)(d0 + dl) * KCODES + k0 + tx];
            T[tx][dl] = v;
            sq += v * v;
        }
        __syncthreads();
        int kr = tid >> 3;            // 0..31
        int dc = (tid & 7) * 4;       // 0..28
        float4 w = make_float4(T[kr][dc], T[kr][dc + 1], T[kr][dc + 2], T[kr][dc + 3]);
        *(float4*)&embedT[(long)(k0 + kr) * DIM + d0 + dc] = w;
    }
    ps[ty][tx] = sq;
    __syncthreads();
    if (ty == 0) {
        float s = 0.f;
        #pragma unroll
        for (int i = 0; i < 8; ++i) s += ps[i][tx];
        enorm[k0 + tx] = s;
    }
}

// ---------------- fused distance GEMM + argmin (half of the code range) ----------------
// score(n,k) = ||e_k||^2 - 2 * dot(xn_n, e_k)   (||xn||^2 dropped: argmin-invariant)
// blockIdx: bit0 = half (ct 0..3 vs 4..7), rest = row tile. Math is R1-verbatim:
// per (row,code) a single sequential fp32 FMA chain over k ascending.
__global__ __launch_bounds__(256, 4) void dist_half(
    const float* __restrict__ x, const float* __restrict__ embed,
    const float* __restrict__ scale, const float* __restrict__ shift,
    const float* __restrict__ enorm, float* __restrict__ pv, int* __restrict__ pi) {
    __shared__ __attribute__((aligned(16))) float As[BK][AS_STRIDE];  // [d'][row]
    __shared__ __attribute__((aligned(16))) float Bs[BK][AS_STRIDE];  // [d'][code]
    __shared__ __attribute__((aligned(16))) float sc_s[DIM];
    __shared__ __attribute__((aligned(16))) float sh_s[DIM];

    int tid = threadIdx.x;
    int tx = tid & 15;       // code group 0..15
    int ty = tid >> 4;       // row group 0..15
    int half = blockIdx.x & 1;
    long row0 = (long)(blockIdx.x >> 1) * BM;

    sc_s[tid] = scale[tid];
    sh_s[tid] = shift[tid];

    float runV[8];
    int   runI[8];
    #pragma unroll
    for (int i = 0; i < 8; ++i) { runV[i] = 3.4e38f; runI[i] = 0; }

    for (int ct = half * 4; ct < half * 4 + 4; ++ct) {
        float acc[8][8];
        #pragma unroll
        for (int i = 0; i < 8; ++i)
            #pragma unroll
            for (int j = 0; j < 8; ++j) acc[i][j] = 0.f;

        for (int dk = 0; dk < DIM; dk += BK) {
            __syncthreads();  // previous compute done before restaging
            // ---- stage A (normalize on the fly): As[d'][r]
            {
                int dq = tid & 7;            // d' = dq*4 .. dq*4+3
                int rb = tid >> 3;           // 0..31
                float4 scv = *(const float4*)&sc_s[dk + dq * 4];
                float4 shv = *(const float4*)&sh_s[dk + dq * 4];
                #pragma unroll
                for (int p = 0; p < 4; ++p) {
                    int r = rb + p * 32;
                    float4 v = *(const float4*)&x[(row0 + r) * DIM + dk + dq * 4];
                    As[dq * 4 + 0][r] = v.x * scv.x + shv.x;
                    As[dq * 4 + 1][r] = v.y * scv.y + shv.y;
                    As[dq * 4 + 2][r] = v.z * scv.z + shv.z;
                    As[dq * 4 + 3][r] = v.w * scv.w + shv.w;
                }
            }
            // ---- stage B: Bs[d'][c]
            {
                int c4 = tid & 31;           // code 4-group
                int dr = tid >> 5;           // 0..7
                #pragma unroll
                for (int p = 0; p < 4; ++p) {
                    int dl = dr + p * 8;
                    float4 v = *(const float4*)&embed[(long)(dk + dl) * KCODES + ct * BNT + c4 * 4];
                    *(float4*)&Bs[dl][c4 * 4] = v;
                }
            }
            __syncthreads();
            // ---- compute: 8x8 micro-tile, cols {tx*4..+3} U {64+tx*4..+3}
            #pragma unroll 8
            for (int kk = 0; kk < BK; ++kk) {
                float4 a0 = *(const float4*)&As[kk][ty * 8];
                float4 a1 = *(const float4*)&As[kk][ty * 8 + 4];
                float4 b0 = *(const float4*)&Bs[kk][tx * 4];
                float4 b1 = *(const float4*)&Bs[kk][64 + tx * 4];
                float a[8] = {a0.x, a0.y, a0.z, a0.w, a1.x, a1.y, a1.z, a1.w};
                float b[8] = {b0.x, b0.y, b0.z, b0.w, b1.x, b1.y, b1.z, b1.w};
                #pragma unroll
                for (int i = 0; i < 8; ++i)
                    #pragma unroll
                    for (int j = 0; j < 8; ++j) acc[i][j] += a[i] * b[j];
            }
        }
        // ---- epilogue: scores + running argmin (R1-verbatim)
        float4 en0 = *(const float4*)&enorm[ct * BNT + tx * 4];
        float4 en1 = *(const float4*)&enorm[ct * BNT + 64 + tx * 4];
        float en[8] = {en0.x, en0.y, en0.z, en0.w, en1.x, en1.y, en1.z, en1.w};
        int col0 = ct * BNT + tx * 4;
        int col1 = ct * BNT + 64 + tx * 4;
        #pragma unroll
        for (int i = 0; i < 8; ++i) {
            float bv = 3.4e38f;
            int bi = 0;
            #pragma unroll
            for (int j = 0; j < 8; ++j) {
                float s = en[j] - 2.0f * acc[i][j];
                int col = (j < 4) ? (col0 + j) : (col1 + (j - 4));
                if (s < bv) { bv = s; bi = col; }       // ascending cols: first-min kept
            }
            // butterfly min across the 16 lanes sharing these rows (tie -> smaller idx)
            #pragma unroll
            for (int m = 1; m < 16; m <<= 1) {
                float ov = __shfl_xor(bv, m);
                int   oi = __shfl_xor(bi, m);
                if (ov < bv || (ov == bv && oi < bi)) { bv = ov; bi = oi; }
            }
            if (bv < runV[i] || (bv == runV[i] && bi < runI[i])) { runV[i] = bv; runI[i] = bi; }
        }
    }
    if (tx == 0) {
        #pragma unroll
        for (int i = 0; i < 8; ++i) {
            long row = row0 + ty * 8 + i;
            pv[(long)half * N_ROWS + row] = runV[i];
            pi[(long)half * N_ROWS + row] = runI[i];
        }
    }
}

// ---------------- merge halves (half0 wins ties: i0 < i1 always) ----------------
__global__ void merge_halves(const float* __restrict__ pv, const int* __restrict__ pi,
                             int* __restrict__ bestIdx) {
    int r = blockIdx.x * 256 + threadIdx.x;
    float v0 = pv[r], v1 = pv[N_ROWS + r];
    int i0 = pi[r], i1 = pi[N_ROWS + r];
    bestIdx[r] = (v1 < v0) ? i1 : i0;    // equal -> half0 (smaller index), matches R1's
                                          // sequential ct semantics exactly
}

// ---------------- gather codebook rows + diff partials ----------------
__global__ void gather_out(const float* __restrict__ x, const float* __restrict__ embedT,
                           const float* __restrict__ scale, const float* __restrict__ shift,
                           const int* __restrict__ bestIdx, float* __restrict__ out,
                           float* __restrict__ diffPart) {
    __shared__ float wsum[4];
    int tid = threadIdx.x;
    int wave = tid >> 6, lane = tid & 63;
    long row = (long)blockIdx.x * 4 + wave;
    int k = bestIdx[row];
    int d0 = lane * 4;
    float4 q  = *(const float4*)&embedT[(long)k * DIM + d0];
    float4 xv = *(const float4*)&x[row * DIM + d0];
    float4 sc = *(const float4*)&scale[d0];
    float4 sh = *(const float4*)&shift[d0];
    float xn0 = xv.x * sc.x + sh.x;
    float xn1 = xv.y * sc.y + sh.y;
    float xn2 = xv.z * sc.z + sh.z;
    float xn3 = xv.w * sc.w + sh.w;
    *(float4*)&out[row * DIM + d0] = q;
    float d0f = q.x - xn0, d1f = q.y - xn1, d2f = q.z - xn2, d3f = q.w - xn3;
    float dsq = d0f * d0f + d1f * d1f + d2f * d2f + d3f * d3f;
    #pragma unroll
    for (int m = 32; m; m >>= 1) dsq += __shfl_xor(dsq, m);
    if (lane == 0) wsum[wave] = dsq;
    __syncthreads();
    if (tid == 0) diffPart[blockIdx.x] = wsum[0] + wsum[1] + wsum[2] + wsum[3];
}

// ---------------- final diff reduce ----------------
__global__ void diff_final(const float* __restrict__ diffPart, float* __restrict__ outDiff) {
    __shared__ float s[256];
    int tid = threadIdx.x;
    float a = 0.f;
    for (int i = tid; i < E_BLOCKS; i += 256) a += diffPart[i];
    s[tid] = a;
    __syncthreads();
    for (int st = 128; st; st >>= 1) {
        if (tid < st) s[tid] += s[tid + st];
        __syncthreads();
    }
    if (tid == 0) outDiff[0] = s[0] * (1.0f / (float)(N_ROWS * DIM));
}

extern "C" void kernel_launch(void* const* d_in, const int* in_sizes, int n_in,
                              void* d_out, int out_size, void* d_ws, size_t ws_size,
                              hipStream_t stream) {
    const float* x     = (const float*)d_in[0];
    const float* embed = (const float*)d_in[1];
    const float* gamma = (const float*)d_in[2];
    const float* beta  = (const float*)d_in[3];
    float* out = (float*)d_out;

    // ws layout — R1-exact byte offsets (proven extent 2,430,976 B)
    char* w = (char*)d_ws;
    float* pSum    = (float*)(w);                 // [0, 512K)        bn only
    float* pSq     = (float*)(w + 524288);        // [512K, 1M)       bn only
    float* pv      = (float*)(w);                 // overlays dead pSum: 2*65536*4 = 512K
    int*   pi      = (int*)(w + 524288);          // overlays dead pSq: 512K
    float* scale   = (float*)(w + 1048576);       // 1 KB
    float* shift   = (float*)(w + 1049600);       // 1 KB
    float* embedT  = (float*)(w + 1050624);       // 1 MB
    float* enorm   = (float*)(w + 2099200);       // 4 KB
    int*   bestIdx = (int*)(w + 2103296);         // 256 KB
    float* diffPart= (float*)(w + 2365440);       // 64 KB -> ends 2430976

    bn_partial<<<STAT_BLOCKS, 256, 0, stream>>>(x, pSum, pSq);
    bn_finalize<<<1, 256, 0, stream>>>(pSum, pSq, gamma, beta, scale, shift);
    embed_prep<<<KCODES / 32, 256, 0, stream>>>(embed, embedT, enorm);
    dist_half<<<(N_ROWS / BM) * 2, 256, 0, stream>>>(x, embed, scale, shift, enorm, pv, pi);
    merge_halves<<<N_ROWS / 256, 256, 0, stream>>>(pv, pi, bestIdx);
    gather_out<<<E_BLOCKS, 256, 0, stream>>>(x, embedT, scale, shift, bestIdx, out, diffPart);
    diff_final<<<1, 256, 0, stream>>>(diffPart, out + (long)N_ROWS * DIM);
}

// Round 8
// 492.498 us; speedup vs baseline: 1.0894x; 1.0274x over previous
//
#include <hip/hip_runtime.h>

// VQ-VAE Quantize: BN1d(batch stats) -> argmin L2 vs codebook -> gather + diff
// R8: R1/R7's exact fp32 score arithmetic (bit-frozen: per (row,code) one
// sequential FMA chain over d ascending). Structural-only changes:
//   - per-(row-tile, code-tile) blocks: 512 x 8 = 4096 blocks (stagger, tail)
//   - T14 async staging: next d-chunk loaded to regs during compute
//   - deterministic merge via u64 atomicMin on (encoded score | idx)

#define N_ROWS 65536
#define DIM 256
#define KCODES 1024
#define BN_EPS_F 1e-5f

#define STAT_BLOCKS 512      // 128 rows each
#define BM 128               // row tile
#define BNT 128              // code tile (8 tiles cover K)
#define BK 32                // d-chunk
#define AS_STRIDE 132        // 128 + 4 pad
#define E_BLOCKS 16384       // gather blocks: 4 rows each

// ---------------- BN statistics: stage 1 ----------------
__global__ void bn_partial(const float* __restrict__ x, float* __restrict__ pSum,
                           float* __restrict__ pSq) {
    int t = threadIdx.x;
    int b = blockIdx.x;
    long base = (long)b * 128 * DIM;
    float s = 0.f, q = 0.f;
    for (int r = 0; r < 128; ++r) {
        float v = x[base + (long)r * DIM + t];
        s += v; q += v * v;
    }
    pSum[b * DIM + t] = s;
    pSq[b * DIM + t] = q;
}

// ---------------- BN statistics: stage 2 ----------------
__global__ void bn_finalize(const float* __restrict__ pSum, const float* __restrict__ pSq,
                            const float* __restrict__ gamma, const float* __restrict__ beta,
                            float* __restrict__ scale, float* __restrict__ shift) {
    int t = threadIdx.x;
    float s = 0.f, q = 0.f;
    for (int b = 0; b < STAT_BLOCKS; ++b) {
        s += pSum[b * DIM + t];
        q += pSq[b * DIM + t];
    }
    float mean = s * (1.0f / (float)N_ROWS);
    float var  = q * (1.0f / (float)N_ROWS) - mean * mean;  // biased var
    var = fmaxf(var, 0.f);
    float sc = gamma[t] * rsqrtf(var + BN_EPS_F);
    scale[t] = sc;
    shift[t] = beta[t] - mean * sc;
}

// ---------------- embed prep: transpose to [K][D] + squared norms ----------------
__global__ void embed_prep(const float* __restrict__ embed, float* __restrict__ embedT,
                           float* __restrict__ enorm) {
    __shared__ float T[32][33];
    __shared__ float ps[8][32];
    int tid = threadIdx.x;
    int tx = tid & 31;
    int ty = tid >> 5;
    int k0 = blockIdx.x * 32;
    float sq = 0.f;
    for (int d0 = 0; d0 < DIM; d0 += 32) {
        __syncthreads();
        #pragma unroll
        for (int p = 0; p < 4; ++p) {
            int dl = ty + p * 8;
            float v = embed[(long)(d0 + dl) * KCODES + k0 + tx];
            T[tx][dl] = v;
            sq += v * v;
        }
        __syncthreads();
        int kr = tid >> 3;
        int dc = (tid & 7) * 4;
        float4 w = make_float4(T[kr][dc], T[kr][dc + 1], T[kr][dc + 2], T[kr][dc + 3]);
        *(float4*)&embedT[(long)(k0 + kr) * DIM + d0 + dc] = w;
    }
    ps[ty][tx] = sq;
    __syncthreads();
    if (ty == 0) {
        float s = 0.f;
        #pragma unroll
        for (int i = 0; i < 8; ++i) s += ps[i][tx];
        enorm[k0 + tx] = s;
    }
}

// ---------------- init packed (score,idx) minima ----------------
__global__ void init_packed(unsigned long long* __restrict__ packed) {
    packed[blockIdx.x * 256 + threadIdx.x] = ~0ULL;
}

// ---------------- fused distance GEMM + argmin (one 128-code tile) ----------------
// score(n,k) = ||e_k||^2 - 2 * dot(xn_n, e_k); expressions R7-verbatim.
// blockIdx: low 3 bits = ct (code tile), rest = row tile.
__global__ __launch_bounds__(256, 4) void dist_ct(
    const float* __restrict__ x, const float* __restrict__ embed,
    const float* __restrict__ scale, const float* __restrict__ shift,
    const float* __restrict__ enorm, unsigned long long* __restrict__ packed) {
    __shared__ __attribute__((aligned(16))) float As[BK][AS_STRIDE];  // [d'][row]
    __shared__ __attribute__((aligned(16))) float Bs[BK][AS_STRIDE];  // [d'][code]
    __shared__ __attribute__((aligned(16))) float sc_s[DIM];
    __shared__ __attribute__((aligned(16))) float sh_s[DIM];

    int tid = threadIdx.x;
    int tx = tid & 15;       // code group 0..15
    int ty = tid >> 4;       // row group 0..15
    int ct = blockIdx.x & 7;
    long row0 = (long)(blockIdx.x >> 3) * BM;

    sc_s[tid] = scale[tid];
    sh_s[tid] = shift[tid];

    float acc[8][8];
    #pragma unroll
    for (int i = 0; i < 8; ++i)
        #pragma unroll
        for (int j = 0; j < 8; ++j) acc[i][j] = 0.f;

    // staging thread mapping (R7-identical addresses)
    int dq = tid & 7, rb = tid >> 3;     // A: d'=dq*4.., rows rb+p*32
    int c4 = tid & 31, dr = tid >> 5;    // B: codes c4*4, d'=dr+p*8

    // T14 prologue: preload dk=0 into regs
    float4 rA[4], rB[4];
    #pragma unroll
    for (int p = 0; p < 4; ++p)
        rA[p] = *(const float4*)&x[(row0 + rb + p * 32) * DIM + dq * 4];
    #pragma unroll
    for (int p = 0; p < 4; ++p)
        rB[p] = *(const float4*)&embed[(long)(dr + p * 8) * KCODES + ct * BNT + c4 * 4];

    for (int dk = 0; dk < DIM; dk += BK) {
        __syncthreads();   // previous compute done before overwriting buffers
        // ---- write staged regs -> LDS (normalize A exactly as R7)
        {
            float4 scv = *(const float4*)&sc_s[dk + dq * 4];
            float4 shv = *(const float4*)&sh_s[dk + dq * 4];
            #pragma unroll
            for (int p = 0; p < 4; ++p) {
                int r = rb + p * 32;
                As[dq * 4 + 0][r] = rA[p].x * scv.x + shv.x;
                As[dq * 4 + 1][r] = rA[p].y * scv.y + shv.y;
                As[dq * 4 + 2][r] = rA[p].z * scv.z + shv.z;
                As[dq * 4 + 3][r] = rA[p].w * scv.w + shv.w;
            }
            #pragma unroll
            for (int p = 0; p < 4; ++p)
                *(float4*)&Bs[dr + p * 8][c4 * 4] = rB[p];
        }
        __syncthreads();
        // ---- T14: issue next chunk's loads; latency hides under compute below
        if (dk + BK < DIM) {
            #pragma unroll
            for (int p = 0; p < 4; ++p)
                rA[p] = *(const float4*)&x[(row0 + rb + p * 32) * DIM + (dk + BK) + dq * 4];
            #pragma unroll
            for (int p = 0; p < 4; ++p)
                rB[p] = *(const float4*)&embed[(long)((dk + BK) + dr + p * 8) * KCODES + ct * BNT + c4 * 4];
        }
        // ---- compute: 8x8 micro-tile (bit-frozen chain, d ascending)
        #pragma unroll 8
        for (int kk = 0; kk < BK; ++kk) {
            float4 a0 = *(const float4*)&As[kk][ty * 8];
            float4 a1 = *(const float4*)&As[kk][ty * 8 + 4];
            float4 b0 = *(const float4*)&Bs[kk][tx * 4];
            float4 b1 = *(const float4*)&Bs[kk][64 + tx * 4];
            float a[8] = {a0.x, a0.y, a0.z, a0.w, a1.x, a1.y, a1.z, a1.w};
            float b[8] = {b0.x, b0.y, b0.z, b0.w, b1.x, b1.y, b1.z, b1.w};
            #pragma unroll
            for (int i = 0; i < 8; ++i)
                #pragma unroll
                for (int j = 0; j < 8; ++j) acc[i][j] += a[i] * b[j];
        }
    }
    // ---- epilogue: scores + per-ct candidate + deterministic global merge
    float4 en0 = *(const float4*)&enorm[ct * BNT + tx * 4];
    float4 en1 = *(const float4*)&enorm[ct * BNT + 64 + tx * 4];
    float en[8] = {en0.x, en0.y, en0.z, en0.w, en1.x, en1.y, en1.z, en1.w};
    int col0 = ct * BNT + tx * 4;
    int col1 = ct * BNT + 64 + tx * 4;
    #pragma unroll
    for (int i = 0; i < 8; ++i) {
        float bv = 3.4e38f;
        int bi = 0;
        #pragma unroll
        for (int j = 0; j < 8; ++j) {
            float s = en[j] - 2.0f * acc[i][j];
            int col = (j < 4) ? (col0 + j) : (col1 + (j - 4));
            if (s < bv) { bv = s; bi = col; }           // ascending cols: first-min kept
        }
        #pragma unroll
        for (int m = 1; m < 16; m <<= 1) {
            float ov = __shfl_xor(bv, m);
            int   oi = __shfl_xor(bi, m);
            if (ov < bv || (ov == bv && oi < bi)) { bv = ov; bi = oi; }
        }
        if (tx == 0) {
            float t = bv + 0.0f;                         // fold -0.0 -> +0.0
            unsigned ub = __float_as_uint(t);
            unsigned enc = (t >= 0.f) ? (ub ^ 0x80000000u) : ~ub;  // order-preserving
            unsigned long long pk = ((unsigned long long)enc << 32) | (unsigned)bi;
            atomicMin(&packed[row0 + ty * 8 + i], pk);   // lexicographic (score, idx) min
        }
    }
}

// ---------------- gather codebook rows + diff partials ----------------
__global__ void gather_out(const float* __restrict__ x, const float* __restrict__ embedT,
                           const float* __restrict__ scale, const float* __restrict__ shift,
                           const unsigned long long* __restrict__ packed, float* __restrict__ out,
                           float* __restrict__ diffPart) {
    __shared__ float wsum[4];
    int tid = threadIdx.x;
    int wave = tid >> 6, lane = tid & 63;
    long row = (long)blockIdx.x * 4 + wave;
    int k = (int)(unsigned)(packed[row] & 0xFFFFFFFFULL);
    int d0 = lane * 4;
    float4 q  = *(const float4*)&embedT[(long)k * DIM + d0];
    float4 xv = *(const float4*)&x[row * DIM + d0];
    float4 sc = *(const float4*)&scale[d0];
    float4 sh = *(const float4*)&shift[d0];
    float xn0 = xv.x * sc.x + sh.x;
    float xn1 = xv.y * sc.y + sh.y;
    float xn2 = xv.z * sc.z + sh.z;
    float xn3 = xv.w * sc.w + sh.w;
    *(float4*)&out[row * DIM + d0] = q;
    float d0f = q.x - xn0, d1f = q.y - xn1, d2f = q.z - xn2, d3f = q.w - xn3;
    float dsq = d0f * d0f + d1f * d1f + d2f * d2f + d3f * d3f;
    #pragma unroll
    for (int m = 32; m; m >>= 1) dsq += __shfl_xor(dsq, m);
    if (lane == 0) wsum[wave] = dsq;
    __syncthreads();
    if (tid == 0) diffPart[blockIdx.x] = wsum[0] + wsum[1] + wsum[2] + wsum[3];
}

// ---------------- final diff reduce ----------------
__global__ void diff_final(const float* __restrict__ diffPart, float* __restrict__ outDiff) {
    __shared__ float s[256];
    int tid = threadIdx.x;
    float a = 0.f;
    for (int i = tid; i < E_BLOCKS; i += 256) a += diffPart[i];
    s[tid] = a;
    __syncthreads();
    for (int st = 128; st; st >>= 1) {
        if (tid < st) s[tid] += s[tid + st];
        __syncthreads();
    }
    if (tid == 0) outDiff[0] = s[0] * (1.0f / (float)(N_ROWS * DIM));
}

extern "C" void kernel_launch(void* const* d_in, const int* in_sizes, int n_in,
                              void* d_out, int out_size, void* d_ws, size_t ws_size,
                              hipStream_t stream) {
    const float* x     = (const float*)d_in[0];
    const float* embed = (const float*)d_in[1];
    const float* gamma = (const float*)d_in[2];
    const float* beta  = (const float*)d_in[3];
    float* out = (float*)d_out;

    // ws layout — same proven extent (2,430,976 B)
    char* w = (char*)d_ws;
    float* pSum    = (float*)(w);                 // [0, 512K)   bn only
    float* pSq     = (float*)(w + 524288);        // [512K, 1M)  bn only
    unsigned long long* packed = (unsigned long long*)(w);  // 512K, overlays dead pSum
    float* scale   = (float*)(w + 1048576);       // 1 KB
    float* shift   = (float*)(w + 1049600);       // 1 KB
    float* embedT  = (float*)(w + 1050624);       // 1 MB
    float* enorm   = (float*)(w + 2099200);       // 4 KB
    float* diffPart= (float*)(w + 2365440);       // 64 KB -> ends 2430976

    bn_partial<<<STAT_BLOCKS, 256, 0, stream>>>(x, pSum, pSq);
    bn_finalize<<<1, 256, 0, stream>>>(pSum, pSq, gamma, beta, scale, shift);
    init_packed<<<N_ROWS / 256, 256, 0, stream>>>(packed);
    embed_prep<<<KCODES / 32, 256, 0, stream>>>(embed, embedT, enorm);
    dist_ct<<<(N_ROWS / BM) * 8, 256, 0, stream>>>(x, embed, scale, shift, enorm, packed);
    gather_out<<<E_BLOCKS, 256, 0, stream>>>(x, embedT, scale, shift, packed, out, diffPart);
    diff_final<<<1, 256, 0, stream>>>(diffPart, out + (long)N_ROWS * DIM);
}

// Round 9
// 489.197 us; speedup vs baseline: 1.0967x; 1.0067x over previous
//
#include <hip/hip_runtime.h>

// VQ-VAE Quantize: BN1d(batch stats) -> argmin L2 vs codebook -> gather + diff
// R9: R8 with XCD-local grid decomposition for dist_ct:
//   ct = blockIdx >> 9, rt = blockIdx & 511  (was ct = low bits)
// => a row-tile's 8 code-tile blocks all land on the same XCD (blockIdx mod 8
//    is invariant), so x row-tiles are fetched once per XCD instead of 8x.
// Score arithmetic remains bit-frozen (R1/R7 chain: per (row,code) one
// sequential fp32 FMA chain over d ascending).

#define N_ROWS 65536
#define DIM 256
#define KCODES 1024
#define BN_EPS_F 1e-5f

#define STAT_BLOCKS 512      // 128 rows each
#define BM 128               // row tile
#define BNT 128              // code tile (8 tiles cover K)
#define BK 32                // d-chunk
#define AS_STRIDE 132        // 128 + 4 pad
#define E_BLOCKS 16384       // gather blocks: 4 rows each

// ---------------- BN statistics: stage 1 ----------------
__global__ void bn_partial(const float* __restrict__ x, float* __restrict__ pSum,
                           float* __restrict__ pSq) {
    int t = threadIdx.x;
    int b = blockIdx.x;
    long base = (long)b * 128 * DIM;
    float s = 0.f, q = 0.f;
    for (int r = 0; r < 128; ++r) {
        float v = x[base + (long)r * DIM + t];
        s += v; q += v * v;
    }
    pSum[b * DIM + t] = s;
    pSq[b * DIM + t] = q;
}

// ---------------- BN statistics: stage 2 ----------------
__global__ void bn_finalize(const float* __restrict__ pSum, const float* __restrict__ pSq,
                            const float* __restrict__ gamma, const float* __restrict__ beta,
                            float* __restrict__ scale, float* __restrict__ shift) {
    int t = threadIdx.x;
    float s = 0.f, q = 0.f;
    for (int b = 0; b < STAT_BLOCKS; ++b) {
        s += pSum[b * DIM + t];
        q += pSq[b * DIM + t];
    }
    float mean = s * (1.0f / (float)N_ROWS);
    float var  = q * (1.0f / (float)N_ROWS) - mean * mean;  // biased var
    var = fmaxf(var, 0.f);
    float sc = gamma[t] * rsqrtf(var + BN_EPS_F);
    scale[t] = sc;
    shift[t] = beta[t] - mean * sc;
}

// ---------------- embed prep: transpose to [K][D] + squared norms ----------------
__global__ void embed_prep(const float* __restrict__ embed, float* __restrict__ embedT,
                           float* __restrict__ enorm) {
    __shared__ float T[32][33];
    __shared__ float ps[8][32];
    int tid = threadIdx.x;
    int tx = tid & 31;
    int ty = tid >> 5;
    int k0 = blockIdx.x * 32;
    float sq = 0.f;
    for (int d0 = 0; d0 < DIM; d0 += 32) {
        __syncthreads();
        #pragma unroll
        for (int p = 0; p < 4; ++p) {
            int dl = ty + p * 8;
            float v = embed[(long)(d0 + dl) * KCODES + k0 + tx];
            T[tx][dl] = v;
            sq += v * v;
        }
        __syncthreads();
        int kr = tid >> 3;
        int dc = (tid & 7) * 4;
        float4 w = make_float4(T[kr][dc], T[kr][dc + 1], T[kr][dc + 2], T[kr][dc + 3]);
        *(float4*)&embedT[(long)(k0 + kr) * DIM + d0 + dc] = w;
    }
    ps[ty][tx] = sq;
    __syncthreads();
    if (ty == 0) {
        float s = 0.f;
        #pragma unroll
        for (int i = 0; i < 8; ++i) s += ps[i][tx];
        enorm[k0 + tx] = s;
    }
}

// ---------------- init packed (score,idx) minima ----------------
__global__ void init_packed(unsigned long long* __restrict__ packed) {
    packed[blockIdx.x * 256 + threadIdx.x] = ~0ULL;
}

// ---------------- fused distance GEMM + argmin (one 128-code tile) ----------------
// score(n,k) = ||e_k||^2 - 2 * dot(xn_n, e_k); expressions R7-verbatim.
// blockIdx: high bits = ct (code tile), low 9 bits = row tile (XCD-local).
__global__ __launch_bounds__(256, 4) void dist_ct(
    const float* __restrict__ x, const float* __restrict__ embed,
    const float* __restrict__ scale, const float* __restrict__ shift,
    const float* __restrict__ enorm, unsigned long long* __restrict__ packed) {
    __shared__ __attribute__((aligned(16))) float As[BK][AS_STRIDE];  // [d'][row]
    __shared__ __attribute__((aligned(16))) float Bs[BK][AS_STRIDE];  // [d'][code]
    __shared__ __attribute__((aligned(16))) float sc_s[DIM];
    __shared__ __attribute__((aligned(16))) float sh_s[DIM];

    int tid = threadIdx.x;
    int tx = tid & 15;       // code group 0..15
    int ty = tid >> 4;       // row group 0..15
    int ct = blockIdx.x >> 9;                 // 0..7
    long row0 = (long)(blockIdx.x & 511) * BM;

    sc_s[tid] = scale[tid];
    sh_s[tid] = shift[tid];

    float acc[8][8];
    #pragma unroll
    for (int i = 0; i < 8; ++i)
        #pragma unroll
        for (int j = 0; j < 8; ++j) acc[i][j] = 0.f;

    // staging thread mapping (R7-identical addresses)
    int dq = tid & 7, rb = tid >> 3;     // A: d'=dq*4.., rows rb+p*32
    int c4 = tid & 31, dr = tid >> 5;    // B: codes c4*4, d'=dr+p*8

    // T14 prologue: preload dk=0 into regs
    float4 rA[4], rB[4];
    #pragma unroll
    for (int p = 0; p < 4; ++p)
        rA[p] = *(const float4*)&x[(row0 + rb + p * 32) * DIM + dq * 4];
    #pragma unroll
    for (int p = 0; p < 4; ++p)
        rB[p] = *(const float4*)&embed[(long)(dr + p * 8) * KCODES + ct * BNT + c4 * 4];

    for (int dk = 0; dk < DIM; dk += BK) {
        __syncthreads();   // previous compute done before overwriting buffers
        // ---- write staged regs -> LDS (normalize A exactly as R7)
        {
            float4 scv = *(const float4*)&sc_s[dk + dq * 4];
            float4 shv = *(const float4*)&sh_s[dk + dq * 4];
            #pragma unroll
            for (int p = 0; p < 4; ++p) {
                int r = rb + p * 32;
                As[dq * 4 + 0][r] = rA[p].x * scv.x + shv.x;
                As[dq * 4 + 1][r] = rA[p].y * scv.y + shv.y;
                As[dq * 4 + 2][r] = rA[p].z * scv.z + shv.z;
                As[dq * 4 + 3][r] = rA[p].w * scv.w + shv.w;
            }
            #pragma unroll
            for (int p = 0; p < 4; ++p)
                *(float4*)&Bs[dr + p * 8][c4 * 4] = rB[p];
        }
        __syncthreads();
        // ---- T14: issue next chunk's loads; latency hides under compute below
        if (dk + BK < DIM) {
            #pragma unroll
            for (int p = 0; p < 4; ++p)
                rA[p] = *(const float4*)&x[(row0 + rb + p * 32) * DIM + (dk + BK) + dq * 4];
            #pragma unroll
            for (int p = 0; p < 4; ++p)
                rB[p] = *(const float4*)&embed[(long)((dk + BK) + dr + p * 8) * KCODES + ct * BNT + c4 * 4];
        }
        // ---- compute: 8x8 micro-tile (bit-frozen chain, d ascending)
        #pragma unroll 8
        for (int kk = 0; kk < BK; ++kk) {
            float4 a0 = *(const float4*)&As[kk][ty * 8];
            float4 a1 = *(const float4*)&As[kk][ty * 8 + 4];
            float4 b0 = *(const float4*)&Bs[kk][tx * 4];
            float4 b1 = *(const float4*)&Bs[kk][64 + tx * 4];
            float a[8] = {a0.x, a0.y, a0.z, a0.w, a1.x, a1.y, a1.z, a1.w};
            float b[8] = {b0.x, b0.y, b0.z, b0.w, b1.x, b1.y, b1.z, b1.w};
            #pragma unroll
            for (int i = 0; i < 8; ++i)
                #pragma unroll
                for (int j = 0; j < 8; ++j) acc[i][j] += a[i] * b[j];
        }
    }
    // ---- epilogue: scores + per-ct candidate + deterministic global merge
    float4 en0 = *(const float4*)&enorm[ct * BNT + tx * 4];
    float4 en1 = *(const float4*)&enorm[ct * BNT + 64 + tx * 4];
    float en[8] = {en0.x, en0.y, en0.z, en0.w, en1.x, en1.y, en1.z, en1.w};
    int col0 = ct * BNT + tx * 4;
    int col1 = ct * BNT + 64 + tx * 4;
    #pragma unroll
    for (int i = 0; i < 8; ++i) {
        float bv = 3.4e38f;
        int bi = 0;
        #pragma unroll
        for (int j = 0; j < 8; ++j) {
            float s = en[j] - 2.0f * acc[i][j];
            int col = (j < 4) ? (col0 + j) : (col1 + (j - 4));
            if (s < bv) { bv = s; bi = col; }           // ascending cols: first-min kept
        }
        #pragma unroll
        for (int m = 1; m < 16; m <<= 1) {
            float ov = __shfl_xor(bv, m);
            int   oi = __shfl_xor(bi, m);
            if (ov < bv || (ov == bv && oi < bi)) { bv = ov; bi = oi; }
        }
        if (tx == 0) {
            float t = bv + 0.0f;                         // fold -0.0 -> +0.0
            unsigned ub = __float_as_uint(t);
            unsigned enc = (t >= 0.f) ? (ub ^ 0x80000000u) : ~ub;  // order-preserving
            unsigned long long pk = ((unsigned long long)enc << 32) | (unsigned)bi;
            atomicMin(&packed[row0 + ty * 8 + i], pk);   // lexicographic (score, idx) min
        }
    }
}

// ---------------- gather codebook rows + diff partials ----------------
__global__ void gather_out(const float* __restrict__ x, const float* __restrict__ embedT,
                           const float* __restrict__ scale, const float* __restrict__ shift,
                           const unsigned long long* __restrict__ packed, float* __restrict__ out,
                           float* __restrict__ diffPart) {
    __shared__ float wsum[4];
    int tid = threadIdx.x;
    int wave = tid >> 6, lane = tid & 63;
    long row = (long)blockIdx.x * 4 + wave;
    int k = (int)(unsigned)(packed[row] & 0xFFFFFFFFULL);
    int d0 = lane * 4;
    float4 q  = *(const float4*)&embedT[(long)k * DIM + d0];
    float4 xv = *(const float4*)&x[row * DIM + d0];
    float4 sc = *(const float4*)&scale[d0];
    float4 sh = *(const float4*)&shift[d0];
    float xn0 = xv.x * sc.x + sh.x;
    float xn1 = xv.y * sc.y + sh.y;
    float xn2 = xv.z * sc.z + sh.z;
    float xn3 = xv.w * sc.w + sh.w;
    *(float4*)&out[row * DIM + d0] = q;
    float d0f = q.x - xn0, d1f = q.y - xn1, d2f = q.z - xn2, d3f = q.w - xn3;
    float dsq = d0f * d0f + d1f * d1f + d2f * d2f + d3f * d3f;
    #pragma unroll
    for (int m = 32; m; m >>= 1) dsq += __shfl_xor(dsq, m);
    if (lane == 0) wsum[wave] = dsq;
    __syncthreads();
    if (tid == 0) diffPart[blockIdx.x] = wsum[0] + wsum[1] + wsum[2] + wsum[3];
}

// ---------------- final diff reduce ----------------
__global__ void diff_final(const float* __restrict__ diffPart, float* __restrict__ outDiff) {
    __shared__ float s[256];
    int tid = threadIdx.x;
    float a = 0.f;
    for (int i = tid; i < E_BLOCKS; i += 256) a += diffPart[i];
    s[tid] = a;
    __syncthreads();
    for (int st = 128; st; st >>= 1) {
        if (tid < st) s[tid] += s[tid + st];
        __syncthreads();
    }
    if (tid == 0) outDiff[0] = s[0] * (1.0f / (float)(N_ROWS * DIM));
}

extern "C" void kernel_launch(void* const* d_in, const int* in_sizes, int n_in,
                              void* d_out, int out_size, void* d_ws, size_t ws_size,
                              hipStream_t stream) {
    const float* x     = (const float*)d_in[0];
    const float* embed = (const float*)d_in[1];
    const float* gamma = (const float*)d_in[2];
    const float* beta  = (const float*)d_in[3];
    float* out = (float*)d_out;

    // ws layout — same proven extent (2,430,976 B)
    char* w = (char*)d_ws;
    float* pSum    = (float*)(w);                 // [0, 512K)   bn only
    float* pSq     = (float*)(w + 524288);        // [512K, 1M)  bn only
    unsigned long long* packed = (unsigned long long*)(w);  // 512K, overlays dead pSum
    float* scale   = (float*)(w + 1048576);       // 1 KB
    float* shift   = (float*)(w + 1049600);       // 1 KB
    float* embedT  = (float*)(w + 1050624);       // 1 MB
    float* enorm   = (float*)(w + 2099200);       // 4 KB
    float* diffPart= (float*)(w + 2365440);       // 64 KB -> ends 2430976

    bn_partial<<<STAT_BLOCKS, 256, 0, stream>>>(x, pSum, pSq);
    bn_finalize<<<1, 256, 0, stream>>>(pSum, pSq, gamma, beta, scale, shift);
    init_packed<<<N_ROWS / 256, 256, 0, stream>>>(packed);
    embed_prep<<<KCODES / 32, 256, 0, stream>>>(embed, embedT, enorm);
    dist_ct<<<(N_ROWS / BM) * 8, 256, 0, stream>>>(x, embed, scale, shift, enorm, packed);
    gather_out<<<E_BLOCKS, 256, 0, stream>>>(x, embedT, scale, shift, packed, out, diffPart);
    diff_final<<<1, 256, 0, stream>>>(diffPart, out + (long)N_ROWS * DIM);
}

// Round 10
// 460.892 us; speedup vs baseline: 1.1641x; 1.0614x over previous
//
#include <hip/hip_runtime.h>

// VQ-VAE Quantize: BN1d(batch stats) -> argmin L2 vs codebook -> gather + diff
// R10: fix R8/R9 regressions found in counters:
//   (1) WRITE_SIZE 432 MB = scratch spills from T14 prefetch regs -> revert to
//       R7's direct staging (no long-lived prefetch registers, no spill).
//   (2) FETCH unchanged in R9 because same-XCD ct-blocks were 512 slots apart
//       -> swizzle phys = (rt&7) | (ct<<3) | ((rt>>3)<<6): 8 ct-blocks of a
//       row-tile are 8 apart (co-resident) AND same XCD -> x fetched once/XCD.
// Score arithmetic bit-frozen (R1/R7): per (row,code) one sequential fp32 FMA
// chain over d ascending; deterministic u64 atomicMin merge (proven R8/R9).

#define N_ROWS 65536
#define DIM 256
#define KCODES 1024
#define BN_EPS_F 1e-5f

#define STAT_BLOCKS 512      // 128 rows each
#define BM 128               // row tile
#define BNT 128              // code tile (8 tiles cover K)
#define BK 32                // d-chunk
#define AS_STRIDE 132        // 128 + 4 pad
#define E_BLOCKS 16384       // gather blocks: 4 rows each

// ---------------- BN statistics: stage 1 ----------------
__global__ void bn_partial(const float* __restrict__ x, float* __restrict__ pSum,
                           float* __restrict__ pSq) {
    int t = threadIdx.x;
    int b = blockIdx.x;
    long base = (long)b * 128 * DIM;
    float s = 0.f, q = 0.f;
    for (int r = 0; r < 128; ++r) {
        float v = x[base + (long)r * DIM + t];
        s += v; q += v * v;
    }
    pSum[b * DIM + t] = s;
    pSq[b * DIM + t] = q;
}

// ---------------- BN statistics: stage 2 ----------------
__global__ void bn_finalize(const float* __restrict__ pSum, const float* __restrict__ pSq,
                            const float* __restrict__ gamma, const float* __restrict__ beta,
                            float* __restrict__ scale, float* __restrict__ shift) {
    int t = threadIdx.x;
    float s = 0.f, q = 0.f;
    for (int b = 0; b < STAT_BLOCKS; ++b) {
        s += pSum[b * DIM + t];
        q += pSq[b * DIM + t];
    }
    float mean = s * (1.0f / (float)N_ROWS);
    float var  = q * (1.0f / (float)N_ROWS) - mean * mean;  // biased var
    var = fmaxf(var, 0.f);
    float sc = gamma[t] * rsqrtf(var + BN_EPS_F);
    scale[t] = sc;
    shift[t] = beta[t] - mean * sc;
}

// ---------------- embed prep: transpose to [K][D] + squared norms ----------------
__global__ void embed_prep(const float* __restrict__ embed, float* __restrict__ embedT,
                           float* __restrict__ enorm) {
    __shared__ float T[32][33];
    __shared__ float ps[8][32];
    int tid = threadIdx.x;
    int tx = tid & 31;
    int ty = tid >> 5;
    int k0 = blockIdx.x * 32;
    float sq = 0.f;
    for (int d0 = 0; d0 < DIM; d0 += 32) {
        __syncthreads();
        #pragma unroll
        for (int p = 0; p < 4; ++p) {
            int dl = ty + p * 8;
            float v = embed[(long)(d0 + dl) * KCODES + k0 + tx];
            T[tx][dl] = v;
            sq += v * v;
        }
        __syncthreads();
        int kr = tid >> 3;
        int dc = (tid & 7) * 4;
        float4 w = make_float4(T[kr][dc], T[kr][dc + 1], T[kr][dc + 2], T[kr][dc + 3]);
        *(float4*)&embedT[(long)(k0 + kr) * DIM + d0 + dc] = w;
    }
    ps[ty][tx] = sq;
    __syncthreads();
    if (ty == 0) {
        float s = 0.f;
        #pragma unroll
        for (int i = 0; i < 8; ++i) s += ps[i][tx];
        enorm[k0 + tx] = s;
    }
}

// ---------------- init packed (score,idx) minima ----------------
__global__ void init_packed(unsigned long long* __restrict__ packed) {
    packed[blockIdx.x * 256 + threadIdx.x] = ~0ULL;
}

// ---------------- fused distance GEMM + argmin (one 128-code tile) ----------------
// score(n,k) = ||e_k||^2 - 2 * dot(xn_n, e_k); expressions R7-verbatim.
// blockIdx swizzle: ct = (phys>>3)&7, rt = (phys&7) | ((phys>>6)<<3)
//   -> the 8 ct-blocks of a row-tile are 8 apart in dispatch AND same XCD.
__global__ __launch_bounds__(256, 4) void dist_ct(
    const float* __restrict__ x, const float* __restrict__ embed,
    const float* __restrict__ scale, const float* __restrict__ shift,
    const float* __restrict__ enorm, unsigned long long* __restrict__ packed) {
    __shared__ __attribute__((aligned(16))) float As[BK][AS_STRIDE];  // [d'][row]
    __shared__ __attribute__((aligned(16))) float Bs[BK][AS_STRIDE];  // [d'][code]
    __shared__ __attribute__((aligned(16))) float sc_s[DIM];
    __shared__ __attribute__((aligned(16))) float sh_s[DIM];

    int tid = threadIdx.x;
    int tx = tid & 15;       // code group 0..15
    int ty = tid >> 4;       // row group 0..15
    int phys = blockIdx.x;
    int ct = (phys >> 3) & 7;
    long rt = (long)((phys & 7) | ((phys >> 6) << 3));
    long row0 = rt * BM;

    sc_s[tid] = scale[tid];
    sh_s[tid] = shift[tid];

    float acc[8][8];
    #pragma unroll
    for (int i = 0; i < 8; ++i)
        #pragma unroll
        for (int j = 0; j < 8; ++j) acc[i][j] = 0.f;

    for (int dk = 0; dk < DIM; dk += BK) {
        __syncthreads();  // previous compute done before restaging
        // ---- stage A (normalize on the fly): As[d'][r]  (R7-verbatim)
        {
            int dq = tid & 7;            // d' = dq*4 .. dq*4+3
            int rb = tid >> 3;           // 0..31
            float4 scv = *(const float4*)&sc_s[dk + dq * 4];
            float4 shv = *(const float4*)&sh_s[dk + dq * 4];
            #pragma unroll
            for (int p = 0; p < 4; ++p) {
                int r = rb + p * 32;
                float4 v = *(const float4*)&x[(row0 + r) * DIM + dk + dq * 4];
                As[dq * 4 + 0][r] = v.x * scv.x + shv.x;
                As[dq * 4 + 1][r] = v.y * scv.y + shv.y;
                As[dq * 4 + 2][r] = v.z * scv.z + shv.z;
                As[dq * 4 + 3][r] = v.w * scv.w + shv.w;
            }
        }
        // ---- stage B: Bs[d'][c]  (R7-verbatim)
        {
            int c4 = tid & 31;           // code 4-group
            int dr = tid >> 5;           // 0..7
            #pragma unroll
            for (int p = 0; p < 4; ++p) {
                int dl = dr + p * 8;
                float4 v = *(const float4*)&embed[(long)(dk + dl) * KCODES + ct * BNT + c4 * 4];
                *(float4*)&Bs[dl][c4 * 4] = v;
            }
        }
        __syncthreads();
        // ---- compute: 8x8 micro-tile (bit-frozen chain, d ascending)
        #pragma unroll 8
        for (int kk = 0; kk < BK; ++kk) {
            float4 a0 = *(const float4*)&As[kk][ty * 8];
            float4 a1 = *(const float4*)&As[kk][ty * 8 + 4];
            float4 b0 = *(const float4*)&Bs[kk][tx * 4];
            float4 b1 = *(const float4*)&Bs[kk][64 + tx * 4];
            float a[8] = {a0.x, a0.y, a0.z, a0.w, a1.x, a1.y, a1.z, a1.w};
            float b[8] = {b0.x, b0.y, b0.z, b0.w, b1.x, b1.y, b1.z, b1.w};
            #pragma unroll
            for (int i = 0; i < 8; ++i)
                #pragma unroll
                for (int j = 0; j < 8; ++j) acc[i][j] += a[i] * b[j];
        }
    }
    // ---- epilogue: scores + per-ct candidate + deterministic global merge
    float4 en0 = *(const float4*)&enorm[ct * BNT + tx * 4];
    float4 en1 = *(const float4*)&enorm[ct * BNT + 64 + tx * 4];
    float en[8] = {en0.x, en0.y, en0.z, en0.w, en1.x, en1.y, en1.z, en1.w};
    int col0 = ct * BNT + tx * 4;
    int col1 = ct * BNT + 64 + tx * 4;
    #pragma unroll
    for (int i = 0; i < 8; ++i) {
        float bv = 3.4e38f;
        int bi = 0;
        #pragma unroll
        for (int j = 0; j < 8; ++j) {
            float s = en[j] - 2.0f * acc[i][j];
            int col = (j < 4) ? (col0 + j) : (col1 + (j - 4));
            if (s < bv) { bv = s; bi = col; }           // ascending cols: first-min kept
        }
        #pragma unroll
        for (int m = 1; m < 16; m <<= 1) {
            float ov = __shfl_xor(bv, m);
            int   oi = __shfl_xor(bi, m);
            if (ov < bv || (ov == bv && oi < bi)) { bv = ov; bi = oi; }
        }
        if (tx == 0) {
            float t = bv + 0.0f;                         // fold -0.0 -> +0.0
            unsigned ub = __float_as_uint(t);
            unsigned enc = (t >= 0.f) ? (ub ^ 0x80000000u) : ~ub;  // order-preserving
            unsigned long long pk = ((unsigned long long)enc << 32) | (unsigned)bi;
            atomicMin(&packed[row0 + ty * 8 + i], pk);   // lexicographic (score, idx) min
        }
    }
}

// ---------------- gather codebook rows + diff partials ----------------
__global__ void gather_out(const float* __restrict__ x, const float* __restrict__ embedT,
                           const float* __restrict__ scale, const float* __restrict__ shift,
                           const unsigned long long* __restrict__ packed, float* __restrict__ out,
                           float* __restrict__ diffPart) {
    __shared__ float wsum[4];
    int tid = threadIdx.x;
    int wave = tid >> 6, lane = tid & 63;
    long row = (long)blockIdx.x * 4 + wave;
    int k = (int)(unsigned)(packed[row] & 0xFFFFFFFFULL);
    int d0 = lane * 4;
    float4 q  = *(const float4*)&embedT[(long)k * DIM + d0];
    float4 xv = *(const float4*)&x[row * DIM + d0];
    float4 sc = *(const float4*)&scale[d0];
    float4 sh = *(const float4*)&shift[d0];
    float xn0 = xv.x * sc.x + sh.x;
    float xn1 = xv.y * sc.y + sh.y;
    float xn2 = xv.z * sc.z + sh.z;
    float xn3 = xv.w * sc.w + sh.w;
    *(float4*)&out[row * DIM + d0] = q;
    float d0f = q.x - xn0, d1f = q.y - xn1, d2f = q.z - xn2, d3f = q.w - xn3;
    float dsq = d0f * d0f + d1f * d1f + d2f * d2f + d3f * d3f;
    #pragma unroll
    for (int m = 32; m; m >>= 1) dsq += __shfl_xor(dsq, m);
    if (lane == 0) wsum[wave] = dsq;
    __syncthreads();
    if (tid == 0) diffPart[blockIdx.x] = wsum[0] + wsum[1] + wsum[2] + wsum[3];
}

// ---------------- final diff reduce ----------------
__global__ void diff_final(const float* __restrict__ diffPart, float* __restrict__ outDiff) {
    __shared__ float s[256];
    int tid = threadIdx.x;
    float a = 0.f;
    for (int i = tid; i < E_BLOCKS; i += 256) a += diffPart[i];
    s[tid] = a;
    __syncthreads();
    for (int st = 128; st; st >>= 1) {
        if (tid < st) s[tid] += s[tid + st];
        __syncthreads();
    }
    if (tid == 0) outDiff[0] = s[0] * (1.0f / (float)(N_ROWS * DIM));
}

extern "C" void kernel_launch(void* const* d_in, const int* in_sizes, int n_in,
                              void* d_out, int out_size, void* d_ws, size_t ws_size,
                              hipStream_t stream) {
    const float* x     = (const float*)d_in[0];
    const float* embed = (const float*)d_in[1];
    const float* gamma = (const float*)d_in[2];
    const float* beta  = (const float*)d_in[3];
    float* out = (float*)d_out;

    // ws layout — same proven extent (2,430,976 B)
    char* w = (char*)d_ws;
    float* pSum    = (float*)(w);                 // [0, 512K)   bn only
    float* pSq     = (float*)(w + 524288);        // [512K, 1M)  bn only
    unsigned long long* packed = (unsigned long long*)(w);  // 512K, overlays dead pSum
    float* scale   = (float*)(w + 1048576);       // 1 KB
    float* shift   = (float*)(w + 1049600);       // 1 KB
    float* embedT  = (float*)(w + 1050624);       // 1 MB
    float* enorm   = (float*)(w + 2099200);       // 4 KB
    float* diffPart= (float*)(w + 2365440);       // 64 KB -> ends 2430976

    bn_partial<<<STAT_BLOCKS, 256, 0, stream>>>(x, pSum, pSq);
    bn_finalize<<<1, 256, 0, stream>>>(pSum, pSq, gamma, beta, scale, shift);
    init_packed<<<N_ROWS / 256, 256, 0, stream>>>(packed);
    embed_prep<<<KCODES / 32, 256, 0, stream>>>(embed, embedT, enorm);
    dist_ct<<<(N_ROWS / BM) * 8, 256, 0, stream>>>(x, embed, scale, shift, enorm, packed);
    gather_out<<<E_BLOCKS, 256, 0, stream>>>(x, embedT, scale, shift, packed, out, diffPart);
    diff_final<<<1, 256, 0, stream>>>(diffPart, out + (long)N_ROWS * DIM);
}

// Round 11
// 442.257 us; speedup vs baseline: 1.2132x; 1.0421x over previous
//
#include <hip/hip_runtime.h>

// VQ-VAE Quantize: BN1d(batch stats) -> argmin L2 vs codebook -> gather + diff
// R11: R10 + packed-fp32 inner loop (v_pk_fma_f32, VOP3P). Bit-exact: every
// (row,code) chain is still the identical sequence of single-rounded fp32 FMAs
// over d ascending — packing only pairs INDEPENDENT chains per instruction.
// a-operand broadcast via op_sel (even row: lo, odd row: hi), b/acc pairs are
// natural adjacent VGPR pairs. Everything else (swizzle, staging, merge) = R10.

#define N_ROWS 65536
#define DIM 256
#define KCODES 1024
#define BN_EPS_F 1e-5f

#define STAT_BLOCKS 512      // 128 rows each
#define BM 128               // row tile
#define BNT 128              // code tile (8 tiles cover K)
#define BK 32                // d-chunk
#define AS_STRIDE 132        // 128 + 4 pad
#define E_BLOCKS 16384       // gather blocks: 4 rows each

typedef __attribute__((ext_vector_type(2))) float f32x2;
typedef __attribute__((ext_vector_type(4))) float f32x4v;

// ---------------- BN statistics: stage 1 ----------------
__global__ void bn_partial(const float* __restrict__ x, float* __restrict__ pSum,
                           float* __restrict__ pSq) {
    int t = threadIdx.x;
    int b = blockIdx.x;
    long base = (long)b * 128 * DIM;
    float s = 0.f, q = 0.f;
    for (int r = 0; r < 128; ++r) {
        float v = x[base + (long)r * DIM + t];
        s += v; q += v * v;
    }
    pSum[b * DIM + t] = s;
    pSq[b * DIM + t] = q;
}

// ---------------- BN statistics: stage 2 ----------------
__global__ void bn_finalize(const float* __restrict__ pSum, const float* __restrict__ pSq,
                            const float* __restrict__ gamma, const float* __restrict__ beta,
                            float* __restrict__ scale, float* __restrict__ shift) {
    int t = threadIdx.x;
    float s = 0.f, q = 0.f;
    for (int b = 0; b < STAT_BLOCKS; ++b) {
        s += pSum[b * DIM + t];
        q += pSq[b * DIM + t];
    }
    float mean = s * (1.0f / (float)N_ROWS);
    float var  = q * (1.0f / (float)N_ROWS) - mean * mean;  // biased var
    var = fmaxf(var, 0.f);
    float sc = gamma[t] * rsqrtf(var + BN_EPS_F);
    scale[t] = sc;
    shift[t] = beta[t] - mean * sc;
}

// ---------------- embed prep: transpose to [K][D] + squared norms ----------------
__global__ void embed_prep(const float* __restrict__ embed, float* __restrict__ embedT,
                           float* __restrict__ enorm) {
    __shared__ float T[32][33];
    __shared__ float ps[8][32];
    int tid = threadIdx.x;
    int tx = tid & 31;
    int ty = tid >> 5;
    int k0 = blockIdx.x * 32;
    float sq = 0.f;
    for (int d0 = 0; d0 < DIM; d0 += 32) {
        __syncthreads();
        #pragma unroll
        for (int p = 0; p < 4; ++p) {
            int dl = ty + p * 8;
            float v = embed[(long)(d0 + dl) * KCODES + k0 + tx];
            T[tx][dl] = v;
            sq += v * v;
        }
        __syncthreads();
        int kr = tid >> 3;
        int dc = (tid & 7) * 4;
        float4 w = make_float4(T[kr][dc], T[kr][dc + 1], T[kr][dc + 2], T[kr][dc + 3]);
        *(float4*)&embedT[(long)(k0 + kr) * DIM + d0 + dc] = w;
    }
    ps[ty][tx] = sq;
    __syncthreads();
    if (ty == 0) {
        float s = 0.f;
        #pragma unroll
        for (int i = 0; i < 8; ++i) s += ps[i][tx];
        enorm[k0 + tx] = s;
    }
}

// ---------------- init packed (score,idx) minima ----------------
__global__ void init_packed(unsigned long long* __restrict__ packed) {
    packed[blockIdx.x * 256 + threadIdx.x] = ~0ULL;
}

// ---------------- fused distance GEMM + argmin (one 128-code tile) ----------------
// score(n,k) = ||e_k||^2 - 2 * dot(xn_n, e_k); chain bit-frozen (R1/R7).
// blockIdx swizzle: ct = (phys>>3)&7, rt = (phys&7) | ((phys>>6)<<3).
__global__ __launch_bounds__(256, 4) void dist_ct(
    const float* __restrict__ x, const float* __restrict__ embed,
    const float* __restrict__ scale, const float* __restrict__ shift,
    const float* __restrict__ enorm, unsigned long long* __restrict__ packed) {
    __shared__ __attribute__((aligned(16))) float As[BK][AS_STRIDE];  // [d'][row]
    __shared__ __attribute__((aligned(16))) float Bs[BK][AS_STRIDE];  // [d'][code]
    __shared__ __attribute__((aligned(16))) float sc_s[DIM];
    __shared__ __attribute__((aligned(16))) float sh_s[DIM];

    int tid = threadIdx.x;
    int tx = tid & 15;       // code group 0..15
    int ty = tid >> 4;       // row group 0..15
    int phys = blockIdx.x;
    int ct = (phys >> 3) & 7;
    long rt = (long)((phys & 7) | ((phys >> 6) << 3));
    long row0 = rt * BM;

    sc_s[tid] = scale[tid];
    sh_s[tid] = shift[tid];

    // packed accumulators: acc2[row i][col-pair jp] = (score-dot for col 2jp, 2jp+1)
    f32x2 acc2[8][4];
    #pragma unroll
    for (int i = 0; i < 8; ++i)
        #pragma unroll
        for (int jp = 0; jp < 4; ++jp) acc2[i][jp] = (f32x2){0.f, 0.f};

    for (int dk = 0; dk < DIM; dk += BK) {
        __syncthreads();  // previous compute done before restaging
        // ---- stage A (normalize on the fly): As[d'][r]  (R7-verbatim)
        {
            int dq = tid & 7;            // d' = dq*4 .. dq*4+3
            int rb = tid >> 3;           // 0..31
            float4 scv = *(const float4*)&sc_s[dk + dq * 4];
            float4 shv = *(const float4*)&sh_s[dk + dq * 4];
            #pragma unroll
            for (int p = 0; p < 4; ++p) {
                int r = rb + p * 32;
                float4 v = *(const float4*)&x[(row0 + r) * DIM + dk + dq * 4];
                As[dq * 4 + 0][r] = v.x * scv.x + shv.x;
                As[dq * 4 + 1][r] = v.y * scv.y + shv.y;
                As[dq * 4 + 2][r] = v.z * scv.z + shv.z;
                As[dq * 4 + 3][r] = v.w * scv.w + shv.w;
            }
        }
        // ---- stage B: Bs[d'][c]  (R7-verbatim)
        {
            int c4 = tid & 31;           // code 4-group
            int dr = tid >> 5;           // 0..7
            #pragma unroll
            for (int p = 0; p < 4; ++p) {
                int dl = dr + p * 8;
                float4 v = *(const float4*)&embed[(long)(dk + dl) * KCODES + ct * BNT + c4 * 4];
                *(float4*)&Bs[dl][c4 * 4] = v;
            }
        }
        __syncthreads();
        // ---- compute: 8x8 micro-tile via v_pk_fma_f32 (2 independent chains/inst)
        #pragma unroll 8
        for (int kk = 0; kk < BK; ++kk) {
            f32x4v a0 = *(const f32x4v*)&As[kk][ty * 8];
            f32x4v a1 = *(const f32x4v*)&As[kk][ty * 8 + 4];
            f32x4v b0 = *(const f32x4v*)&Bs[kk][tx * 4];
            f32x4v b1 = *(const f32x4v*)&Bs[kk][64 + tx * 4];
            f32x2 bp[4] = {
                __builtin_shufflevector(b0, b0, 0, 1),
                __builtin_shufflevector(b0, b0, 2, 3),
                __builtin_shufflevector(b1, b1, 0, 1),
                __builtin_shufflevector(b1, b1, 2, 3)
            };
            f32x2 ap[4] = {
                __builtin_shufflevector(a0, a0, 0, 1),
                __builtin_shufflevector(a0, a0, 2, 3),
                __builtin_shufflevector(a1, a1, 0, 1),
                __builtin_shufflevector(a1, a1, 2, 3)
            };
            #pragma unroll
            for (int ih = 0; ih < 4; ++ih) {           // a-pair index (rows 2ih, 2ih+1)
                #pragma unroll
                for (int jp = 0; jp < 4; ++jp) {
                    // even row 2ih: both halves use ap[ih].lo
                    asm("v_pk_fma_f32 %0, %1, %2, %0 op_sel:[0,0,0] op_sel_hi:[1,0,1]"
                        : "+v"(acc2[2 * ih][jp]) : "v"(bp[jp]), "v"(ap[ih]));
                    // odd row 2ih+1: both halves use ap[ih].hi
                    asm("v_pk_fma_f32 %0, %1, %2, %0 op_sel:[0,1,0] op_sel_hi:[1,1,1]"
                        : "+v"(acc2[2 * ih + 1][jp]) : "v"(bp[jp]), "v"(ap[ih]));
                }
            }
        }
    }
    // ---- epilogue: scores + per-ct candidate + deterministic global merge
    float4 en0 = *(const float4*)&enorm[ct * BNT + tx * 4];
    float4 en1 = *(const float4*)&enorm[ct * BNT + 64 + tx * 4];
    float en[8] = {en0.x, en0.y, en0.z, en0.w, en1.x, en1.y, en1.z, en1.w};
    int col0 = ct * BNT + tx * 4;
    int col1 = ct * BNT + 64 + tx * 4;
    #pragma unroll
    for (int i = 0; i < 8; ++i) {
        float bv = 3.4e38f;
        int bi = 0;
        #pragma unroll
        for (int j = 0; j < 8; ++j) {
            float d = (j & 1) ? acc2[i][j >> 1].y : acc2[i][j >> 1].x;
            float s = en[j] - 2.0f * d;
            int col = (j < 4) ? (col0 + j) : (col1 + (j - 4));
            if (s < bv) { bv = s; bi = col; }           // ascending cols: first-min kept
        }
        #pragma unroll
        for (int m = 1; m < 16; m <<= 1) {
            float ov = __shfl_xor(bv, m);
            int   oi = __shfl_xor(bi, m);
            if (ov < bv || (ov == bv && oi < bi)) { bv = ov; bi = oi; }
        }
        if (tx == 0) {
            float t = bv + 0.0f;                         // fold -0.0 -> +0.0
            unsigned ub = __float_as_uint(t);
            unsigned enc = (t >= 0.f) ? (ub ^ 0x80000000u) : ~ub;  // order-preserving
            unsigned long long pk = ((unsigned long long)enc << 32) | (unsigned)bi;
            atomicMin(&packed[row0 + ty * 8 + i], pk);   // lexicographic (score, idx) min
        }
    }
}

// ---------------- gather codebook rows + diff partials ----------------
__global__ void gather_out(const float* __restrict__ x, const float* __restrict__ embedT,
                           const float* __restrict__ scale, const float* __restrict__ shift,
                           const unsigned long long* __restrict__ packed, float* __restrict__ out,
                           float* __restrict__ diffPart) {
    __shared__ float wsum[4];
    int tid = threadIdx.x;
    int wave = tid >> 6, lane = tid & 63;
    long row = (long)blockIdx.x * 4 + wave;
    int k = (int)(unsigned)(packed[row] & 0xFFFFFFFFULL);
    int d0 = lane * 4;
    float4 q  = *(const float4*)&embedT[(long)k * DIM + d0];
    float4 xv = *(const float4*)&x[row * DIM + d0];
    float4 sc = *(const float4*)&scale[d0];
    float4 sh = *(const float4*)&shift[d0];
    float xn0 = xv.x * sc.x + sh.x;
    float xn1 = xv.y * sc.y + sh.y;
    float xn2 = xv.z * sc.z + sh.z;
    float xn3 = xv.w * sc.w + sh.w;
    *(float4*)&out[row * DIM + d0] = q;
    float d0f = q.x - xn0, d1f = q.y - xn1, d2f = q.z - xn2, d3f = q.w - xn3;
    float dsq = d0f * d0f + d1f * d1f + d2f * d2f + d3f * d3f;
    #pragma unroll
    for (int m = 32; m; m >>= 1) dsq += __shfl_xor(dsq, m);
    if (lane == 0) wsum[wave] = dsq;
    __syncthreads();
    if (tid == 0) diffPart[blockIdx.x] = wsum[0] + wsum[1] + wsum[2] + wsum[3];
}

// ---------------- final diff reduce ----------------
__global__ void diff_final(const float* __restrict__ diffPart, float* __restrict__ outDiff) {
    __shared__ float s[256];
    int tid = threadIdx.x;
    float a = 0.f;
    for (int i = tid; i < E_BLOCKS; i += 256) a += diffPart[i];
    s[tid] = a;
    __syncthreads();
    for (int st = 128; st; st >>= 1) {
        if (tid < st) s[tid] += s[tid + st];
        __syncthreads();
    }
    if (tid == 0) outDiff[0] = s[0] * (1.0f / (float)(N_ROWS * DIM));
}

extern "C" void kernel_launch(void* const* d_in, const int* in_sizes, int n_in,
                              void* d_out, int out_size, void* d_ws, size_t ws_size,
                              hipStream_t stream) {
    const float* x     = (const float*)d_in[0];
    const float* embed = (const float*)d_in[1];
    const float* gamma = (const float*)d_in[2];
    const float* beta  = (const float*)d_in[3];
    float* out = (float*)d_out;

    // ws layout — same proven extent (2,430,976 B)
    char* w = (char*)d_ws;
    float* pSum    = (float*)(w);                 // [0, 512K)   bn only
    float* pSq     = (float*)(w + 524288);        // [512K, 1M)  bn only
    unsigned long long* packed = (unsigned long long*)(w);  // 512K, overlays dead pSum
    float* scale   = (float*)(w + 1048576);       // 1 KB
    float* shift   = (float*)(w + 1049600);       // 1 KB
    float* embedT  = (float*)(w + 1050624);       // 1 MB
    float* enorm   = (float*)(w + 2099200);       // 4 KB
    float* diffPart= (float*)(w + 2365440);       // 64 KB -> ends 2430976

    bn_partial<<<STAT_BLOCKS, 256, 0, stream>>>(x, pSum, pSq);
    bn_finalize<<<1, 256, 0, stream>>>(pSum, pSq, gamma, beta, scale, shift);
    init_packed<<<N_ROWS / 256, 256, 0, stream>>>(packed);
    embed_prep<<<KCODES / 32, 256, 0, stream>>>(embed, embedT, enorm);
    dist_ct<<<(N_ROWS / BM) * 8, 256, 0, stream>>>(x, embed, scale, shift, enorm, packed);
    gather_out<<<E_BLOCKS, 256, 0, stream>>>(x, embedT, scale, shift, packed, out, diffPart);
    diff_final<<<1, 256, 0, stream>>>(diffPart, out + (long)N_ROWS * DIM);
}